// Round 19
// baseline (494.291 us; speedup 1.0000x reference)
//
#include <hip/hip_runtime.h>
#include <hip/hip_bf16.h>
#include <math.h>

typedef __hip_bfloat16 bf16;
typedef float f32x4 __attribute__((ext_vector_type(4)));
typedef short s16x8 __attribute__((ext_vector_type(8)));
typedef short s16x4 __attribute__((ext_vector_type(4)));
typedef unsigned int u32;
typedef unsigned long long u64;

#define NB 8            // batch
#define NROW 1025       // rows per batch (cls + 1024 patches)
#define MTOT (NB*NROW)  // 8200
#define DIMD 512
#define NHEAD 8
#define HD 64
#define MLPD 2048
#define QKVN 2560       // q|k|v|kg|vg concatenated
#define JSTR 1032       // padded row length of transposed V (16B-aligned rows)
#define GTILE 8         // glob softmax j-tiles (129 keys each)

__device__ __forceinline__ float b2f(short u) {
    return __builtin_bit_cast(float, (u32)(unsigned short)u << 16);
}
__device__ __forceinline__ unsigned short f2bfbits(float f) {
    __hip_bfloat16 h = __float2bfloat16(f);
    return __builtin_bit_cast(unsigned short, h);
}
__device__ __forceinline__ void g2lds16(const bf16* g, bf16* l) {
    __builtin_amdgcn_global_load_lds((const __attribute__((address_space(1))) u32*)g,
                                     (__attribute__((address_space(3))) u32*)l, 16, 0, 0);
}

// ---------------------------------------------------------------- batched transpose+cvt
__global__ __launch_bounds__(256) void transpose_cvt_L(
    const float* __restrict__ src, bf16* __restrict__ dst, int K, int N, float scale)
{
    __shared__ float t[32][33];
    const int z = blockIdx.z;
    const float* s = src + (size_t)z * K * N;
    bf16* d = dst + (size_t)z * N * K;
    const int n0 = blockIdx.x * 32, k0 = blockIdx.y * 32;
    const int tx = threadIdx.x, ty = threadIdx.y;
#pragma unroll
    for (int i = 0; i < 32; i += 8)
        t[ty + i][tx] = s[(long)(k0 + ty + i) * N + n0 + tx];
    __syncthreads();
#pragma unroll
    for (int i = 0; i < 32; i += 8)
        d[(long)(n0 + ty + i) * K + k0 + tx] = __float2bfloat16(t[tx][ty + i] * scale);
}

// ---------------------------------------------------------------- qkv weight transposes (z = L*5+s)
__global__ __launch_bounds__(256) void qkvw_t(
    const float* __restrict__ wq, const float* __restrict__ wk, const float* __restrict__ wv,
    const float* __restrict__ wkg, const float* __restrict__ wvg, bf16* __restrict__ qkvT)
{
    __shared__ float t[32][33];
    const int z = blockIdx.z, L = z / 5, s = z % 5;
    const float* srcs[5] = {wq, wk, wv, wkg, wvg};
    const float* src = srcs[s] + (size_t)L * DIMD * DIMD;
    bf16* dst = qkvT + ((size_t)L * QKVN + s * DIMD) * DIMD;
    const float scale = (s == 0) ? 0.125f : 1.f;
    const int n0 = blockIdx.x * 32, k0 = blockIdx.y * 32;
    const int tx = threadIdx.x, ty = threadIdx.y;
#pragma unroll
    for (int i = 0; i < 32; i += 8)
        t[ty + i][tx] = src[(long)(k0 + ty + i) * DIMD + n0 + tx];
    __syncthreads();
#pragma unroll
    for (int i = 0; i < 32; i += 8)
        dst[(long)(n0 + ty + i) * DIMD + k0 + tx] = __float2bfloat16(t[tx][ty + i] * scale);
}

// ---------------------------------------------------------------- bias concat (q scaled)
__global__ __launch_bounds__(256) void build_bias(
    const float* __restrict__ bq, const float* __restrict__ bk, const float* __restrict__ bv,
    const float* __restrict__ bkg, const float* __restrict__ bvg, float* __restrict__ outb)
{
    int idx = blockIdx.x * 256 + threadIdx.x;
    if (idx >= 2 * QKVN) return;
    int L = idx / QKVN, c = idx % QKVN;
    int sec = c >> 9, d = c & 511;
    const float* src = (sec == 0) ? bq : (sec == 1) ? bk : (sec == 2) ? bv : (sec == 3) ? bkg : bvg;
    float v = src[L * DIMD + d];
    if (sec == 0) v *= 0.125f;
    outb[idx] = v;
}

// ---------------------------------------------------------------- im2col v2 -> bf16 A [8192][768]
__global__ __launch_bounds__(256) void im2col(
    const float* __restrict__ img, bf16* __restrict__ A)
{
    const int idx = blockIdx.x * 256 + threadIdx.x;   // < 1048576
    const int pp = idx & 7;
    const int pw = (idx >> 3) & 31;
    const int py = (idx >> 8) & 15;
    const int ph = (idx >> 12) & 31;
    const int b  = idx >> 17;
    const int hh = ph * 16 + py;
    const int w  = pw * 16 + pp * 2;
    const float2 c0 = *(const float2*)(img + (((long)(b * 3 + 0) * 512 + hh) * 512 + w));
    const float2 c1 = *(const float2*)(img + (((long)(b * 3 + 1) * 512 + hh) * 512 + w));
    const float2 c2 = *(const float2*)(img + (((long)(b * 3 + 2) * 512 + hh) * 512 + w));
    const long row = (long)b * 1024 + ph * 32 + pw;
    u32* dst = (u32*)(A + row * 768 + py * 48 + pp * 6);
    dst[0] = (u32)f2bfbits(c0.x) | ((u32)f2bfbits(c1.x) << 16);
    dst[1] = (u32)f2bfbits(c2.x) | ((u32)f2bfbits(c0.y) << 16);
    dst[2] = (u32)f2bfbits(c1.y) | ((u32)f2bfbits(c2.y) << 16);
}

// ---------------------------------------------------------------- cls row init: x[b][0][:] = cls + pos[0]
__global__ __launch_bounds__(256) void cls_row(
    const float* __restrict__ cls, const float* __restrict__ pos, float* __restrict__ x)
{
    const int idx = blockIdx.x * 256 + threadIdx.x;   // < 4096
    const int b = idx >> 9, d = idx & 511;
    x[(long)b * NROW * DIMD + d] = cls[d] + pos[d];
}

// ---------------------------------------------------------------- LayerNorm rows -> bf16
__global__ __launch_bounds__(256) void ln_fwd(
    const float* __restrict__ x, const float* __restrict__ w,
    const float* __restrict__ bb, bf16* __restrict__ y, int Mrows)
{
    const int row = blockIdx.x * 4 + (threadIdx.x >> 6);
    if (row >= Mrows) return;
    const int lane = threadIdx.x & 63;
    const float* xr = x + (long)row * DIMD + lane * 8;
    float4 a = *(const float4*)xr;
    float4 b4 = *(const float4*)(xr + 4);
    float s  = a.x + a.y + a.z + a.w + b4.x + b4.y + b4.z + b4.w;
    float sq = a.x*a.x + a.y*a.y + a.z*a.z + a.w*a.w + b4.x*b4.x + b4.y*b4.y + b4.z*b4.z + b4.w*b4.w;
#pragma unroll
    for (int o = 32; o; o >>= 1) { s += __shfl_xor(s, o); sq += __shfl_xor(sq, o); }
    float mean = s * (1.f / 512.f);
    float rstd = rsqrtf(sq * (1.f / 512.f) - mean * mean + 1e-5f);
    bf16* yr = y + (long)row * DIMD + lane * 8;
    const float* wp = w + lane * 8;
    const float* bp = bb + lane * 8;
    float vals[8] = {a.x, a.y, a.z, a.w, b4.x, b4.y, b4.z, b4.w};
#pragma unroll
    for (int u = 0; u < 8; ++u)
        yr[u] = __float2bfloat16((vals[u] - mean) * rstd * wp[u] + bp[u]);
}

// ---------------------------------------------------------------- GEMM 128x128 (patch embed only now)
// EPI: 4=f32 patch-embed w/ pos fused
template<int EPI>
__global__ __launch_bounds__(256) void gemm128(
    const bf16* __restrict__ A, const bf16* __restrict__ Bt,
    const float* __restrict__ bias,
    float* __restrict__ Cf, bf16* __restrict__ Cb,
    int M, int N, int K, const float* __restrict__ posp, bf16* __restrict__ vTout)
{
    __shared__ bf16 aL[2][128 * 64];
    __shared__ bf16 bL[2][128 * 64];
    const int tid = threadIdx.x, lane = tid & 63, w = tid >> 6;
    const int m0 = blockIdx.y * 128, n0 = blockIdx.x * 128;
    const int wm = w >> 1, wn = w & 1;
    f32x4 acc[4][4] = {};
    const int nk = K >> 6;
    const int srow = lane >> 3;                     // 0..7
    const int scol = ((lane & 7) ^ srow) * 8;       // inverse-swizzled source col (elements)

#define STAGE(buf, kt) do {                                                        \
        _Pragma("unroll")                                                          \
        for (int i = 0; i < 4; ++i) {                                              \
            const int rb = i * 32 + w * 8;                                         \
            long ar = m0 + rb + srow; if (ar >= M) ar = M - 1;                     \
            g2lds16(A  + ar * (long)K + (long)(kt) * 64 + scol, &aL[buf][rb * 64]);\
            g2lds16(Bt + (long)(n0 + rb + srow) * K + (long)(kt) * 64 + scol,      \
                    &bL[buf][rb * 64]);                                            \
        } } while (0)

    STAGE(0, 0);
    __syncthreads();
    int cur = 0;
    const int fr = lane & 15;        // fragment row within 16
    const int lc0 = lane >> 4;       // logical chunk base 0..3
    const int px = lane & 7;         // row-XOR key
    const int arow_b = (wm * 64 + fr) << 7;
    const int brow_b = (wn * 64 + fr) << 7;
    for (int kt = 0; kt < nk; ++kt) {
        if (kt + 1 < nk) STAGE(cur ^ 1, kt + 1);
        const char* aP = (const char*)&aL[cur][0];
        const char* bP = (const char*)&bL[cur][0];
#pragma unroll
        for (int ksub = 0; ksub < 2; ++ksub) {
            const int cb = ((ksub * 4 + lc0) ^ px) << 4;
            s16x8 af[4], bf_[4];
#pragma unroll
            for (int mi = 0; mi < 4; ++mi) af[mi]  = *(const s16x8*)(aP + arow_b + mi * 2048 + cb);
#pragma unroll
            for (int ni = 0; ni < 4; ++ni) bf_[ni] = *(const s16x8*)(bP + brow_b + ni * 2048 + cb);
#pragma unroll
            for (int mi = 0; mi < 4; ++mi)
#pragma unroll
                for (int ni = 0; ni < 4; ++ni)
                    acc[mi][ni] = __builtin_amdgcn_mfma_f32_16x16x32_bf16(af[mi], bf_[ni], acc[mi][ni], 0, 0, 0);
        }
        __syncthreads();
        cur ^= 1;
    }
#undef STAGE
    const int lr = (lane >> 4) * 4, lc = lane & 15;
#pragma unroll
    for (int mi = 0; mi < 4; ++mi) {
        const int gr0 = m0 + wm * 64 + mi * 16 + lr;
#pragma unroll
        for (int ni = 0; ni < 4; ++ni) {
            const int gc = n0 + wn * 64 + ni * 16 + lc;
            const float bv = bias[gc];
#pragma unroll
            for (int j = 0; j < 4; ++j) {
                const int gr = gr0 + j;
                if (gr < M) {
                    float v = acc[mi][ni][j] + bv;
                    const int bb2 = gr >> 10, pidx = gr & 1023;
                    Cf[((long)bb2 * NROW + 1 + pidx) * DIMD + gc]
                        = v + posp[(long)(pidx + 1) * DIMD + gc];
                }
            }
        }
    }
    (void)Cb; (void)vTout;
}

// ---------------------------------------------------------------- narrow-N GEMM (128M x 64N, BK=64), 3 blocks/CU (r14/r18 proven)
// EPIN: 0 = f32 residual add (MLP2); 1 = gelu -> bf16 (MLP1);
//       2 = bf16 + fused V-transpose for cols [1024,1536) (qkv)
template<int EPIN>
__global__ __launch_bounds__(256) void gemm_n64(
    const bf16* __restrict__ A, const bf16* __restrict__ Bt,
    const float* __restrict__ bias, float* __restrict__ Cf, bf16* __restrict__ Cb,
    int M, int N, int K, bf16* __restrict__ vTout)
{
    __shared__ bf16 aL[2][128 * 64];
    __shared__ bf16 bL[2][64 * 64];
    const int tid = threadIdx.x, lane = tid & 63, w = tid >> 6;
    const int m0 = blockIdx.y * 128, n0 = blockIdx.x * 64;
    f32x4 acc[2][4] = {};
    const int nk = K >> 6;
    const int srow = lane >> 3;
    const int scol = ((lane & 7) ^ srow) * 8;

#define STAGEN(buf, kt) do {                                                       \
        _Pragma("unroll")                                                          \
        for (int i = 0; i < 4; ++i) {                                              \
            const int rb = i * 32 + w * 8;                                         \
            long ar = m0 + rb + srow; if (ar >= M) ar = M - 1;                     \
            g2lds16(A + ar * (long)K + (long)(kt) * 64 + scol, &aL[buf][rb * 64]); \
        }                                                                          \
        _Pragma("unroll")                                                          \
        for (int i = 0; i < 2; ++i) {                                              \
            const int rb = i * 32 + w * 8;                                         \
            g2lds16(Bt + (long)(n0 + rb + srow) * K + (long)(kt) * 64 + scol,      \
                    &bL[buf][rb * 64]);                                            \
        } } while (0)

    STAGEN(0, 0);
    __syncthreads();
    int cur = 0;
    const int fr = lane & 15;
    const int lc0 = lane >> 4;
    const int px = lane & 7;
    const int arow_b = (w * 32 + fr) << 7;   // wave w owns output rows w*32..w*32+31
    const int brow_b = fr << 7;
    for (int kt = 0; kt < nk; ++kt) {
        if (kt + 1 < nk) STAGEN(cur ^ 1, kt + 1);
        const char* aP = (const char*)&aL[cur][0];
        const char* bP = (const char*)&bL[cur][0];
#pragma unroll
        for (int ksub = 0; ksub < 2; ++ksub) {
            const int cb = ((ksub * 4 + lc0) ^ px) << 4;
            s16x8 af[2], bf_[4];
#pragma unroll
            for (int mi = 0; mi < 2; ++mi) af[mi]  = *(const s16x8*)(aP + arow_b + mi * 2048 + cb);
#pragma unroll
            for (int ni = 0; ni < 4; ++ni) bf_[ni] = *(const s16x8*)(bP + brow_b + ni * 2048 + cb);
#pragma unroll
            for (int mi = 0; mi < 2; ++mi)
#pragma unroll
                for (int ni = 0; ni < 4; ++ni)
                    acc[mi][ni] = __builtin_amdgcn_mfma_f32_16x16x32_bf16(af[mi], bf_[ni], acc[mi][ni], 0, 0, 0);
        }
        __syncthreads();
        cur ^= 1;
    }
#undef STAGEN
    const int lr = (lane >> 4) * 4, lc = lane & 15;
#pragma unroll
    for (int mi = 0; mi < 2; ++mi) {
        const int gr0 = m0 + w * 32 + mi * 16 + lr;
#pragma unroll
        for (int ni = 0; ni < 4; ++ni) {
            const int gc = n0 + ni * 16 + lc;
            const float bv = bias[gc];
            if (EPIN == 2) {
                unsigned short pk[4];
#pragma unroll
                for (int j = 0; j < 4; ++j) {
                    const int gr = gr0 + j;
                    if (gr < M) {
                        const bf16 hv = __float2bfloat16(acc[mi][ni][j] + bv);
                        Cb[(long)gr * N + gc] = hv;
                        pk[j] = __builtin_bit_cast(unsigned short, hv);
                    } else pk[j] = 0;
                }
                if (gc >= 1024 && gc < 1536) {   // fused V-transpose (uniform per 16-lane group)
                    const int d = gc - 1024;
                    const int bb2 = gr0 / NROW, jj = gr0 - bb2 * NROW;
                    if (jj <= 1021 && gr0 + 3 < M) {
                        u64 pack =  (u64)pk[0] | ((u64)pk[1] << 16)
                                 | ((u64)pk[2] << 32) | ((u64)pk[3] << 48);
                        *(u64*)&vTout[((long)bb2 * 512 + d) * JSTR + jj] = pack;
                    } else {
#pragma unroll
                        for (int j = 0; j < 4; ++j) {
                            const int gr = gr0 + j;
                            if (gr < M) {
                                const int b3 = gr / NROW, j3 = gr - b3 * NROW;
                                vTout[((long)b3 * 512 + d) * JSTR + j3] =
                                    __builtin_bit_cast(bf16, pk[j]);
                            }
                        }
                    }
                }
            } else {
#pragma unroll
                for (int j = 0; j < 4; ++j) {
                    const int gr = gr0 + j;
                    if (gr < M) {
                        const float v = acc[mi][ni][j] + bv;
                        if (EPIN == 0) {
                            Cf[(long)gr * N + gc] += v;
                        } else {
                            const float g = 0.5f * v * (1.f + erff(v * 0.70710678118f));
                            Cb[(long)gr * N + gc] = __float2bfloat16(g);
                        }
                    }
                }
            }
        }
    }
    (void)vTout;
}

// ---------------------------------------------------------------- qg projection (r7/r12 proven): qg_all[b][c]
__global__ __launch_bounds__(256) void qg_proj(
    const bf16* __restrict__ ybf, const float* __restrict__ wqg,
    const float* __restrict__ bqg, float* __restrict__ qg_all)
{
    __shared__ float y0[512];
    const int b = blockIdx.x, tid = threadIdx.x;
    const long rowb = (long)b * NROW;
    for (int d = tid; d < 512; d += 256) y0[d] = __bfloat162float(ybf[rowb * DIMD + d]);
    __syncthreads();
    const int c = blockIdx.y * 256 + tid;
    float a = 0.f;
#pragma unroll 8
    for (int kk = 0; kk < 512; ++kk) a += y0[kk] * wqg[(long)kk * DIMD + c];
    qg_all[b * DIMD + c] = (a + bqg[c]) * 0.125f;
}

// ---------------------------------------------------------------- band + tiled-global attention (one launch, r12 proven)
__global__ __launch_bounds__(256) void band_glob_attn(
    const bf16* __restrict__ qkv, const bf16* __restrict__ vT,
    const float* __restrict__ qg_all, float* __restrict__ gpart, float* __restrict__ x)
{
    __shared__ bf16 KlPl[193 * 72];     // 27792 B: K rows (QK^T phase) / Pl (PV phase) / glob scratch
    __shared__ bf16 Vt[64 * 192];       // 24576 B, [d][k], byte ^= (d&7)<<4
    const int c = blockIdx.x, h = blockIdx.y, b = blockIdx.z;
    const int tid = threadIdx.x, lane = tid & 63, w = tid >> 6;
    const long rowb = (long)b * NROW;
    const int hoff = h * HD;

    if (c >= 16) {
        // ---------------- glob j-tile: keys j0..j0+len-1 vs qg
        const int t = c - 16;                 // 0..GTILE-1
        const int j0 = t * 129;
        const int len = (1025 - j0) < 129 ? (1025 - j0) : 129;
        float* gsh  = (float*)KlPl;
        float* S    = gsh;                    // 129
        float* qgs  = gsh + 160;              // 64
        float* redx = gsh + 224;              // 256
        const int dd = tid & 63, part = tid >> 6;
        if (tid < 64) qgs[tid] = qg_all[b * DIMD + hoff + tid];
        __syncthreads();
        if (tid < len) {
            const bf16* kr = qkv + (rowb + j0 + tid) * QKVN + 1536 + hoff;
            float s = 0.f;
#pragma unroll
            for (int c8 = 0; c8 < 8; ++c8) {
                s16x8 kv = *(const s16x8*)(kr + c8 * 8);
#pragma unroll
                for (int e = 0; e < 8; ++e) s += qgs[c8 * 8 + e] * b2f(kv[e]);
            }
            S[tid] = s;
        }
        __syncthreads();
        float lm = -1e30f;
        for (int j = tid; j < len; j += 256) lm = fmaxf(lm, S[j]);
        redx[tid] = lm; __syncthreads();
        for (int st = 128; st; st >>= 1) { if (tid < st) redx[tid] = fmaxf(redx[tid], redx[tid + st]); __syncthreads(); }
        const float mt = redx[0]; __syncthreads();
        float ls = 0.f;
        for (int j = tid; j < len; j += 256) { float e = __expf(S[j] - mt); S[j] = e; ls += e; }
        redx[tid] = ls; __syncthreads();
        for (int st = 128; st; st >>= 1) { if (tid < st) redx[tid] += redx[tid + st]; __syncthreads(); }
        const float tsum = redx[0];
        __syncthreads();
        float acc = 0.f;
#pragma unroll 4
        for (int j = part; j < len; j += 4)
            acc += S[j] * __bfloat162float(qkv[(rowb + j0 + j) * QKVN + 2048 + hoff + dd]);
        redx[tid] = acc;
        __syncthreads();
        if (part == 0) {
            float* gp = gpart + ((size_t)((b * NHEAD + h) * GTILE + t)) * 66;
            gp[2 + dd] = redx[dd] + redx[64 + dd] + redx[128 + dd] + redx[192 + dd];
            if (dd == 0) { gp[0] = mt; gp[1] = tsum; }
        }
        return;
    }

    // ---------------- band chunk (r11-proven path, unchanged)
    const int qi0 = 1 + c * 64, jbase = qi0 - 64;
    bf16* Kl = KlPl;

    for (int task = tid; task < 193 * 8; task += 256) {
        const int d8 = task & 7, r = task >> 3;
        int j = (r < 192) ? (jbase + r) : 0;
        j = j < 0 ? 0 : (j > 1024 ? 1024 : j);
        s16x8 val = *(const s16x8*)(qkv + (rowb + j) * QKVN + 512 + hoff + d8 * 8);
        *(s16x8*)(Kl + r * 72 + d8 * 8) = val;
    }
    for (int task = tid; task < 64 * 24; task += 256) {
        const int kc = task % 24, d = task / 24;
        int j0 = jbase + kc * 8;
        j0 = j0 < 0 ? 0 : (j0 > 1017 ? 1017 : j0);
        s16x8 v = *(const s16x8*)(vT + ((long)(b * 512 + hoff + d)) * JSTR + j0);
        const int bo = (d * 384 + kc * 16) ^ ((d & 7) << 4);
        *(s16x8*)((char*)Vt + bo) = v;
    }

    const int q = lane & 15, g = lane >> 4;
    const int qg = w * 16 + q;
    s16x8 qf0, qf1;
    {
        const bf16* qp = qkv + (rowb + qi0 + qg) * QKVN + hoff + g * 8;
        qf0 = *(const s16x8*)qp;
        qf1 = *(const s16x8*)(qp + 32);
    }
    __syncthreads();

    f32x4 sc[13] = {};
#pragma unroll
    for (int nt = 0; nt < 13; ++nt) {
        const bf16* kp = Kl + (nt * 16 + q) * 72 + g * 8;
        s16x8 k0 = *(const s16x8*)kp;
        s16x8 k1 = *(const s16x8*)(kp + 32);
        sc[nt] = __builtin_amdgcn_mfma_f32_16x16x32_bf16(k0, qf0, sc[nt], 0, 0, 0);
        sc[nt] = __builtin_amdgcn_mfma_f32_16x16x32_bf16(k1, qf1, sc[nt], 0, 0, 0);
    }

    const int lo_ = (qg > 1 - jbase) ? qg : 1 - jbase;
    const int hi_ = (qg + 128 < 1024 - jbase) ? qg + 128 : 1024 - jbase;
    float m = -1e30f;
#pragma unroll
    for (int nt = 0; nt < 12; ++nt)
#pragma unroll
        for (int j = 0; j < 4; ++j) {
            const int slot = nt * 16 + g * 4 + j;
            float s = (slot >= lo_ && slot <= hi_) ? sc[nt][j] : -1e9f;
            sc[nt][j] = s;
            m = fmaxf(m, s);
        }
#pragma unroll
    for (int j = 0; j < 4; ++j) {
        float s = (g == 0 && j == 0) ? sc[12][j] : -1e9f;
        sc[12][j] = s;
        m = fmaxf(m, s);
    }
    m = fmaxf(m, __shfl_xor(m, 16));
    m = fmaxf(m, __shfl_xor(m, 32));
    float sum = 0.f;
#pragma unroll
    for (int nt = 0; nt < 13; ++nt)
#pragma unroll
        for (int j = 0; j < 4; ++j) {
            float p = __expf(sc[nt][j] - m);
            sc[nt][j] = p;
            sum += p;
        }
    sum += __shfl_xor(sum, 16);
    sum += __shfl_xor(sum, 32);
    const float inv = 1.f / sum;
    const float a0 = __shfl(sc[12][0], q);

    __syncthreads();   // all waves done reading Kl before Pl overwrites it

    char* plw = (char*)KlPl + w * 6144;
#pragma unroll
    for (int nt = 0; nt < 12; ++nt) {
        u32 lo2 = (u32)f2bfbits(sc[nt][0]) | ((u32)f2bfbits(sc[nt][1]) << 16);
        u32 hi2 = (u32)f2bfbits(sc[nt][2]) | ((u32)f2bfbits(sc[nt][3]) << 16);
        const int bo = (q * 384 + (nt * 16 + g * 4) * 2) ^ ((q & 7) << 4);
        *(uint2*)(plw + bo) = make_uint2(lo2, hi2);
    }
    __syncthreads();

    f32x4 ac[4] = {};
#pragma unroll
    for (int ks = 0; ks < 6; ++ks) {
        const int pbo = (q * 384 + (ks * 32 + g * 8) * 2) ^ ((q & 7) << 4);
        s16x8 pf = *(const s16x8*)(plw + pbo);
#pragma unroll
        for (int mt = 0; mt < 4; ++mt) {
            const int d = mt * 16 + q;
            const int vbo = ((d * 192 + ks * 32 + g * 8) * 2) ^ ((d & 7) << 4);
            s16x8 vf = *(const s16x8*)((char*)Vt + vbo);
            ac[mt] = __builtin_amdgcn_mfma_f32_16x16x32_bf16(vf, pf, ac[mt], 0, 0, 0);
        }
    }

    const bf16* v0p = qkv + rowb * QKVN + 1024 + hoff;
    float* xr = x + (rowb + qi0 + qg) * DIMD + hoff;
#pragma unroll
    for (int mt = 0; mt < 4; ++mt) {
        const int d0 = mt * 16 + g * 4;
        const s16x4 vv = *(const s16x4*)(v0p + d0);
        float4 prev = *(float4*)(xr + d0);
        prev.x += (ac[mt][0] + a0 * b2f(vv[0])) * inv;
        prev.y += (ac[mt][1] + a0 * b2f(vv[1])) * inv;
        prev.z += (ac[mt][2] + a0 * b2f(vv[2])) * inv;
        prev.w += (ac[mt][3] + a0 * b2f(vv[3])) * inv;
        *(float4*)(xr + d0) = prev;
    }
}

// ---------------------------------------------------------------- glob merge: combine GTILE partials per (b,h)
__global__ __launch_bounds__(64) void glob_merge(
    const float* __restrict__ gp, float* __restrict__ x)
{
    const int hb = blockIdx.x;          // b*NHEAD + h
    const int b = hb >> 3, h = hb & 7;
    const int dd = threadIdx.x;
    const float* base = gp + (size_t)hb * GTILE * 66;
    float m = -1e30f;
#pragma unroll
    for (int t = 0; t < GTILE; ++t) m = fmaxf(m, base[t * 66]);
    float sum = 0.f, acc = 0.f;
#pragma unroll
    for (int t = 0; t < GTILE; ++t) {
        const float wgt = __expf(base[t * 66] - m);
        sum += wgt * base[t * 66 + 1];
        acc += wgt * base[t * 66 + 2 + dd];
    }
    x[(long)b * NROW * DIMD + h * HD + dd] += acc / sum;
}

// ---------------------------------------------------------------- LN of 8 cls rows -> f32
__global__ __launch_bounds__(512) void lncls(
    const float* __restrict__ x, const float* __restrict__ lw,
    const float* __restrict__ lb, float* __restrict__ out)
{
    const int b = threadIdx.x >> 6, lane = threadIdx.x & 63;
    const int d0 = lane * 8;
    const float* xr = x + (long)b * NROW * DIMD + d0;
    float4 a = *(const float4*)xr;
    float4 b4 = *(const float4*)(xr + 4);
    float s  = a.x + a.y + a.z + a.w + b4.x + b4.y + b4.z + b4.w;
    float sq = a.x*a.x + a.y*a.y + a.z*a.z + a.w*a.w + b4.x*b4.x + b4.y*b4.y + b4.z*b4.z + b4.w*b4.w;
#pragma unroll
    for (int o = 32; o; o >>= 1) { s += __shfl_xor(s, o); sq += __shfl_xor(sq, o); }
    const float mean = s * (1.f / 512.f);
    const float rstd = rsqrtf(sq * (1.f / 512.f) - mean * mean + 1e-5f);
    float vals[8] = {a.x, a.y, a.z, a.w, b4.x, b4.y, b4.z, b4.w};
#pragma unroll
    for (int u = 0; u < 8; ++u)
        out[b * DIMD + d0 + u] = (vals[u] - mean) * rstd * lw[d0 + u] + lb[d0 + u];
}

// ---------------------------------------------------------------- head GEMV: thread per (b, class)
__global__ __launch_bounds__(128) void head_gemv(
    const float* __restrict__ lnc, const float* __restrict__ hw,
    const float* __restrict__ hb, float* __restrict__ out)
{
    const int idx = blockIdx.x * 128 + threadIdx.x;
    if (idx >= NB * 1000) return;
    const int b = idx / 1000, cc = idx - b * 1000;
    const float* lr = lnc + b * DIMD;
    float a = hb[cc];
#pragma unroll 8
    for (int kk = 0; kk < 512; ++kk) a += lr[kk] * hw[(long)kk * 1000 + cc];
    out[idx] = a;
}

// ================================================================ launch
extern "C" void kernel_launch(void* const* d_in, const int* in_sizes, int n_in,
                              void* d_out, int out_size, void* d_ws, size_t ws_size,
                              hipStream_t stream)
{
    const float* img     = (const float*)d_in[0];
    const float* patch_w = (const float*)d_in[1];
    const float* patch_b = (const float*)d_in[2];
    const float* cls_tok = (const float*)d_in[3];
    const float* pos_emb = (const float*)d_in[4];
    const float* ln1_w   = (const float*)d_in[5];
    const float* ln1_b   = (const float*)d_in[6];
    const float* wq  = (const float*)d_in[7];
    const float* bq  = (const float*)d_in[8];
    const float* wk  = (const float*)d_in[9];
    const float* bk  = (const float*)d_in[10];
    const float* wv  = (const float*)d_in[11];
    const float* bv  = (const float*)d_in[12];
    const float* wqg = (const float*)d_in[13];
    const float* bqg = (const float*)d_in[14];
    const float* wkg = (const float*)d_in[15];
    const float* bkg = (const float*)d_in[16];
    const float* wvg = (const float*)d_in[17];
    const float* bvg = (const float*)d_in[18];
    const float* ln2_w = (const float*)d_in[19];
    const float* ln2_b = (const float*)d_in[20];
    const float* w1 = (const float*)d_in[21];
    const float* b1 = (const float*)d_in[22];
    const float* w2 = (const float*)d_in[23];
    const float* b2 = (const float*)d_in[24];
    const float* hlw = (const float*)d_in[25];
    const float* hlb = (const float*)d_in[26];
    const float* hw  = (const float*)d_in[27];
    const float* hb  = (const float*)d_in[28];

    char* wsb = (char*)d_ws;
    size_t o = 0;
    auto carve = [&](size_t n) { size_t r = o; o += (n + 255) & ~(size_t)255; return r; };
    float* x    = (float*)(wsb + carve((size_t)MTOT * DIMD * 4));
    bf16*  ybf  = (bf16*) (wsb + carve((size_t)MTOT * DIMD * 2));
    bf16*  qkv  = (bf16*) (wsb + carve((size_t)MTOT * QKVN * 2));
    bf16*  hbuf = (bf16*) (wsb + carve((size_t)MTOT * MLPD * 2));
    bf16*  vT   = (bf16*) (wsb + carve((size_t)NB * 512 * JSTR * 2));
    bf16*  acol = (bf16*) (wsb + carve((size_t)8192 * 768 * 2));
    bf16*  pwt  = (bf16*) (wsb + carve((size_t)512 * 768 * 2));
    bf16*  qkvT = (bf16*) (wsb + carve((size_t)2 * QKVN * DIMD * 2));
    bf16*  w1t  = (bf16*) (wsb + carve((size_t)2 * MLPD * DIMD * 2));
    bf16*  w2t  = (bf16*) (wsb + carve((size_t)2 * DIMD * MLPD * 2));
    float* catb = (float*)(wsb + carve((size_t)2 * QKVN * 4));
    float* qg_all = (float*)(wsb + carve((size_t)NB * DIMD * 4));
    float* gpart  = (float*)(wsb + carve((size_t)NB * NHEAD * GTILE * 66 * 4));
    float* lnc  = (float*)(wsb + carve((size_t)NB * DIMD * 4));
    (void)ws_size; (void)in_sizes; (void)n_in; (void)out_size;

    dim3 tb(32, 8);
    transpose_cvt_L<<<dim3(16, 24, 1), tb, 0, stream>>>(patch_w, pwt, 768, 512, 1.f);
    qkvw_t<<<dim3(16, 16, 10), tb, 0, stream>>>(wq, wk, wv, wkg, wvg, qkvT);
    transpose_cvt_L<<<dim3(64, 16, 2), tb, 0, stream>>>(w1, w1t, DIMD, MLPD, 1.f);
    transpose_cvt_L<<<dim3(16, 64, 2), tb, 0, stream>>>(w2, w2t, MLPD, DIMD, 1.f);
    build_bias<<<20, 256, 0, stream>>>(bq, bk, bv, bkg, bvg, catb);

    im2col<<<4096, 256, 0, stream>>>(img, acol);
    gemm128<4><<<dim3(4, 64), 256, 0, stream>>>(
        acol, pwt, patch_b, x, nullptr, 8192, 512, 768, pos_emb, nullptr);
    cls_row<<<16, 256, 0, stream>>>(cls_tok, pos_emb, x);

    for (int L = 0; L < 2; ++L) {
        ln_fwd<<<2050, 256, 0, stream>>>(x, ln1_w + L * DIMD, ln1_b + L * DIMD, ybf, MTOT);
        gemm_n64<2><<<dim3(QKVN/64, 65), 256, 0, stream>>>(
            ybf, qkvT + (size_t)L * QKVN * DIMD, catb + L * QKVN, nullptr, qkv,
            MTOT, QKVN, DIMD, vT);
        qg_proj<<<dim3(NB, 2), 256, 0, stream>>>(
            ybf, wqg + (size_t)L * DIMD * DIMD, bqg + L * DIMD, qg_all);
        band_glob_attn<<<dim3(16 + GTILE, NHEAD, NB), 256, 0, stream>>>(
            qkv, vT, qg_all, gpart, x);
        glob_merge<<<NB * NHEAD, 64, 0, stream>>>(gpart, x);
        ln_fwd<<<2050, 256, 0, stream>>>(x, ln2_w + L * DIMD, ln2_b + L * DIMD, ybf, MTOT);
        gemm_n64<1><<<dim3(MLPD/64, 65), 256, 0, stream>>>(
            ybf, w1t + (size_t)L * MLPD * DIMD, b1 + L * MLPD, nullptr, hbuf,
            MTOT, MLPD, DIMD, nullptr);
        gemm_n64<0><<<dim3(DIMD/64, 65), 256, 0, stream>>>(
            hbuf, w2t + (size_t)L * DIMD * MLPD, b2 + L * DIMD, x, nullptr,
            MTOT, DIMD, MLPD, nullptr);
    }
    lncls<<<1, 512, 0, stream>>>(x, hlw, hlb, lnc);
    head_gemv<<<63, 128, 0, stream>>>(lnc, hw, hb, (float*)d_out);
}

// Round 20
// 492.539 us; speedup vs baseline: 1.0036x; 1.0036x over previous
//
#include <hip/hip_runtime.h>
#include <hip/hip_bf16.h>
#include <math.h>

typedef __hip_bfloat16 bf16;
typedef float f32x4 __attribute__((ext_vector_type(4)));
typedef short s16x8 __attribute__((ext_vector_type(8)));
typedef short s16x4 __attribute__((ext_vector_type(4)));
typedef unsigned int u32;
typedef unsigned long long u64;

#define NB 8            // batch
#define NROW 1025       // rows per batch (cls + 1024 patches)
#define MTOT (NB*NROW)  // 8200
#define DIMD 512
#define NHEAD 8
#define HD 64
#define MLPD 2048
#define QKVN 2560       // q|k|v|kg|vg concatenated
#define JSTR 1032       // padded row length of transposed V (16B-aligned rows)
#define GTILE 8         // glob softmax j-tiles (129 keys each)

__device__ __forceinline__ float b2f(short u) {
    return __builtin_bit_cast(float, (u32)(unsigned short)u << 16);
}
__device__ __forceinline__ unsigned short f2bfbits(float f) {
    __hip_bfloat16 h = __float2bfloat16(f);
    return __builtin_bit_cast(unsigned short, h);
}
__device__ __forceinline__ void g2lds16(const bf16* g, bf16* l) {
    __builtin_amdgcn_global_load_lds((const __attribute__((address_space(1))) u32*)g,
                                     (__attribute__((address_space(3))) u32*)l, 16, 0, 0);
}

// ---------------------------------------------------------------- batched transpose+cvt
__global__ __launch_bounds__(256) void transpose_cvt_L(
    const float* __restrict__ src, bf16* __restrict__ dst, int K, int N, float scale)
{
    __shared__ float t[32][33];
    const int z = blockIdx.z;
    const float* s = src + (size_t)z * K * N;
    bf16* d = dst + (size_t)z * N * K;
    const int n0 = blockIdx.x * 32, k0 = blockIdx.y * 32;
    const int tx = threadIdx.x, ty = threadIdx.y;
#pragma unroll
    for (int i = 0; i < 32; i += 8)
        t[ty + i][tx] = s[(long)(k0 + ty + i) * N + n0 + tx];
    __syncthreads();
#pragma unroll
    for (int i = 0; i < 32; i += 8)
        d[(long)(n0 + ty + i) * K + k0 + tx] = __float2bfloat16(t[tx][ty + i] * scale);
}

// ---------------------------------------------------------------- qkv weight transposes (z = L*5+s)
__global__ __launch_bounds__(256) void qkvw_t(
    const float* __restrict__ wq, const float* __restrict__ wk, const float* __restrict__ wv,
    const float* __restrict__ wkg, const float* __restrict__ wvg, bf16* __restrict__ qkvT)
{
    __shared__ float t[32][33];
    const int z = blockIdx.z, L = z / 5, s = z % 5;
    const float* srcs[5] = {wq, wk, wv, wkg, wvg};
    const float* src = srcs[s] + (size_t)L * DIMD * DIMD;
    bf16* dst = qkvT + ((size_t)L * QKVN + s * DIMD) * DIMD;
    const float scale = (s == 0) ? 0.125f : 1.f;
    const int n0 = blockIdx.x * 32, k0 = blockIdx.y * 32;
    const int tx = threadIdx.x, ty = threadIdx.y;
#pragma unroll
    for (int i = 0; i < 32; i += 8)
        t[ty + i][tx] = src[(long)(k0 + ty + i) * DIMD + n0 + tx];
    __syncthreads();
#pragma unroll
    for (int i = 0; i < 32; i += 8)
        dst[(long)(n0 + ty + i) * DIMD + k0 + tx] = __float2bfloat16(t[tx][ty + i] * scale);
}

// ---------------------------------------------------------------- bias concat (q scaled)
__global__ __launch_bounds__(256) void build_bias(
    const float* __restrict__ bq, const float* __restrict__ bk, const float* __restrict__ bv,
    const float* __restrict__ bkg, const float* __restrict__ bvg, float* __restrict__ outb)
{
    int idx = blockIdx.x * 256 + threadIdx.x;
    if (idx >= 2 * QKVN) return;
    int L = idx / QKVN, c = idx % QKVN;
    int sec = c >> 9, d = c & 511;
    const float* src = (sec == 0) ? bq : (sec == 1) ? bk : (sec == 2) ? bv : (sec == 3) ? bkg : bvg;
    float v = src[L * DIMD + d];
    if (sec == 0) v *= 0.125f;
    outb[idx] = v;
}

// ---------------------------------------------------------------- im2col v2 -> bf16 A [8192][768]
__global__ __launch_bounds__(256) void im2col(
    const float* __restrict__ img, bf16* __restrict__ A)
{
    const int idx = blockIdx.x * 256 + threadIdx.x;   // < 1048576
    const int pp = idx & 7;
    const int pw = (idx >> 3) & 31;
    const int py = (idx >> 8) & 15;
    const int ph = (idx >> 12) & 31;
    const int b  = idx >> 17;
    const int hh = ph * 16 + py;
    const int w  = pw * 16 + pp * 2;
    const float2 c0 = *(const float2*)(img + (((long)(b * 3 + 0) * 512 + hh) * 512 + w));
    const float2 c1 = *(const float2*)(img + (((long)(b * 3 + 1) * 512 + hh) * 512 + w));
    const float2 c2 = *(const float2*)(img + (((long)(b * 3 + 2) * 512 + hh) * 512 + w));
    const long row = (long)b * 1024 + ph * 32 + pw;
    u32* dst = (u32*)(A + row * 768 + py * 48 + pp * 6);
    dst[0] = (u32)f2bfbits(c0.x) | ((u32)f2bfbits(c1.x) << 16);
    dst[1] = (u32)f2bfbits(c2.x) | ((u32)f2bfbits(c0.y) << 16);
    dst[2] = (u32)f2bfbits(c1.y) | ((u32)f2bfbits(c2.y) << 16);
}

// ---------------------------------------------------------------- cls row init: x[b][0][:] = cls + pos[0]
__global__ __launch_bounds__(256) void cls_row(
    const float* __restrict__ cls, const float* __restrict__ pos, float* __restrict__ x)
{
    const int idx = blockIdx.x * 256 + threadIdx.x;   // < 4096
    const int b = idx >> 9, d = idx & 511;
    x[(long)b * NROW * DIMD + d] = cls[d] + pos[d];
}

// ---------------------------------------------------------------- LayerNorm rows -> bf16
// gpart != nullptr (ln2 use): rows with row%NROW==0 first fold in the glob-attention
// partials (exactly glob_merge's f32 math), write the merged row back to x, then LN.
__global__ __launch_bounds__(256) void ln_fwd(
    float* __restrict__ x, const float* __restrict__ w,
    const float* __restrict__ bb, bf16* __restrict__ y, int Mrows,
    const float* __restrict__ gpart)
{
    const int row = blockIdx.x * 4 + (threadIdx.x >> 6);
    if (row >= Mrows) return;
    const int lane = threadIdx.x & 63;
    float* xr = x + (long)row * DIMD + lane * 8;
    float4 a = *(const float4*)xr;
    float4 b4 = *(const float4*)(xr + 4);
    float vals[8] = {a.x, a.y, a.z, a.w, b4.x, b4.y, b4.z, b4.w};
    if (gpart != nullptr && (row % NROW) == 0) {      // wave-uniform branch
        const int b = row / NROW;
        const int h = lane >> 3;                      // this lane's 8 dims lie in one head
        const float* base = gpart + ((size_t)(b * NHEAD + h)) * GTILE * 66;
        float m = -1e30f;
#pragma unroll
        for (int t = 0; t < GTILE; ++t) m = fmaxf(m, base[t * 66]);
        float sum = 0.f, accm[8] = {};
#pragma unroll
        for (int t = 0; t < GTILE; ++t) {
            const float wgt = __expf(base[t * 66] - m);
            sum += wgt * base[t * 66 + 1];
#pragma unroll
            for (int u = 0; u < 8; ++u)
                accm[u] += wgt * base[t * 66 + 2 + (((lane & 7) * 8) + u)];
        }
        const float invs = 1.f / sum;
#pragma unroll
        for (int u = 0; u < 8; ++u) vals[u] += accm[u] * invs;
        float4 na = {vals[0], vals[1], vals[2], vals[3]};
        float4 nb = {vals[4], vals[5], vals[6], vals[7]};
        *(float4*)xr = na; *(float4*)(xr + 4) = nb;   // persist merged residual
    }
    float s = 0.f, sq = 0.f;
#pragma unroll
    for (int u = 0; u < 8; ++u) { s += vals[u]; sq += vals[u] * vals[u]; }
#pragma unroll
    for (int o = 32; o; o >>= 1) { s += __shfl_xor(s, o); sq += __shfl_xor(sq, o); }
    const float mean = s * (1.f / 512.f);
    const float rstd = rsqrtf(sq * (1.f / 512.f) - mean * mean + 1e-5f);
    bf16* yr = y + (long)row * DIMD + lane * 8;
    const float* wp = w + lane * 8;
    const float* bp = bb + lane * 8;
#pragma unroll
    for (int u = 0; u < 8; ++u)
        yr[u] = __float2bfloat16((vals[u] - mean) * rstd * wp[u] + bp[u]);
}

// ---------------------------------------------------------------- GEMM 128x128 (patch embed only)
template<int EPI>
__global__ __launch_bounds__(256) void gemm128(
    const bf16* __restrict__ A, const bf16* __restrict__ Bt,
    const float* __restrict__ bias,
    float* __restrict__ Cf, bf16* __restrict__ Cb,
    int M, int N, int K, const float* __restrict__ posp, bf16* __restrict__ vTout)
{
    __shared__ bf16 aL[2][128 * 64];
    __shared__ bf16 bL[2][128 * 64];
    const int tid = threadIdx.x, lane = tid & 63, w = tid >> 6;
    const int m0 = blockIdx.y * 128, n0 = blockIdx.x * 128;
    const int wm = w >> 1, wn = w & 1;
    f32x4 acc[4][4] = {};
    const int nk = K >> 6;
    const int srow = lane >> 3;                     // 0..7
    const int scol = ((lane & 7) ^ srow) * 8;       // inverse-swizzled source col (elements)

#define STAGE(buf, kt) do {                                                        \
        _Pragma("unroll")                                                          \
        for (int i = 0; i < 4; ++i) {                                              \
            const int rb = i * 32 + w * 8;                                         \
            long ar = m0 + rb + srow; if (ar >= M) ar = M - 1;                     \
            g2lds16(A  + ar * (long)K + (long)(kt) * 64 + scol, &aL[buf][rb * 64]);\
            g2lds16(Bt + (long)(n0 + rb + srow) * K + (long)(kt) * 64 + scol,      \
                    &bL[buf][rb * 64]);                                            \
        } } while (0)

    STAGE(0, 0);
    __syncthreads();
    int cur = 0;
    const int fr = lane & 15;        // fragment row within 16
    const int lc0 = lane >> 4;       // logical chunk base 0..3
    const int px = lane & 7;         // row-XOR key
    const int arow_b = (wm * 64 + fr) << 7;
    const int brow_b = (wn * 64 + fr) << 7;
    for (int kt = 0; kt < nk; ++kt) {
        if (kt + 1 < nk) STAGE(cur ^ 1, kt + 1);
        const char* aP = (const char*)&aL[cur][0];
        const char* bP = (const char*)&bL[cur][0];
#pragma unroll
        for (int ksub = 0; ksub < 2; ++ksub) {
            const int cb = ((ksub * 4 + lc0) ^ px) << 4;
            s16x8 af[4], bf_[4];
#pragma unroll
            for (int mi = 0; mi < 4; ++mi) af[mi]  = *(const s16x8*)(aP + arow_b + mi * 2048 + cb);
#pragma unroll
            for (int ni = 0; ni < 4; ++ni) bf_[ni] = *(const s16x8*)(bP + brow_b + ni * 2048 + cb);
#pragma unroll
            for (int mi = 0; mi < 4; ++mi)
#pragma unroll
                for (int ni = 0; ni < 4; ++ni)
                    acc[mi][ni] = __builtin_amdgcn_mfma_f32_16x16x32_bf16(af[mi], bf_[ni], acc[mi][ni], 0, 0, 0);
        }
        __syncthreads();
        cur ^= 1;
    }
#undef STAGE
    const int lr = (lane >> 4) * 4, lc = lane & 15;
#pragma unroll
    for (int mi = 0; mi < 4; ++mi) {
        const int gr0 = m0 + wm * 64 + mi * 16 + lr;
#pragma unroll
        for (int ni = 0; ni < 4; ++ni) {
            const int gc = n0 + wn * 64 + ni * 16 + lc;
            const float bv = bias[gc];
#pragma unroll
            for (int j = 0; j < 4; ++j) {
                const int gr = gr0 + j;
                if (gr < M) {
                    float v = acc[mi][ni][j] + bv;
                    const int bb2 = gr >> 10, pidx = gr & 1023;
                    Cf[((long)bb2 * NROW + 1 + pidx) * DIMD + gc]
                        = v + posp[(long)(pidx + 1) * DIMD + gc];
                }
            }
        }
    }
    (void)Cb; (void)vTout;
}

// ---------------------------------------------------------------- narrow-N GEMM (128M x 64N, BK=64), 3 blocks/CU (r14/r18 proven)
// EPIN: 0 = f32 residual add (MLP2); 1 = gelu -> bf16 (MLP1);
//       2 = bf16 via padded-LDS repack + coalesced stores, + fused V-transpose (qkv)
template<int EPIN>
__global__ __launch_bounds__(256) void gemm_n64(
    const bf16* __restrict__ A, const bf16* __restrict__ Bt,
    const float* __restrict__ bias, float* __restrict__ Cf, bf16* __restrict__ Cb,
    int M, int N, int K, bf16* __restrict__ vTout)
{
    __shared__ bf16 aL[2][128 * 64];
    __shared__ bf16 bL[2][64 * 64];
    const int tid = threadIdx.x, lane = tid & 63, w = tid >> 6;
    const int m0 = blockIdx.y * 128, n0 = blockIdx.x * 64;
    f32x4 acc[2][4] = {};
    const int nk = K >> 6;
    const int srow = lane >> 3;
    const int scol = ((lane & 7) ^ srow) * 8;

#define STAGEN(buf, kt) do {                                                       \
        _Pragma("unroll")                                                          \
        for (int i = 0; i < 4; ++i) {                                              \
            const int rb = i * 32 + w * 8;                                         \
            long ar = m0 + rb + srow; if (ar >= M) ar = M - 1;                     \
            g2lds16(A + ar * (long)K + (long)(kt) * 64 + scol, &aL[buf][rb * 64]); \
        }                                                                          \
        _Pragma("unroll")                                                          \
        for (int i = 0; i < 2; ++i) {                                              \
            const int rb = i * 32 + w * 8;                                         \
            g2lds16(Bt + (long)(n0 + rb + srow) * K + (long)(kt) * 64 + scol,      \
                    &bL[buf][rb * 64]);                                            \
        } } while (0)

    STAGEN(0, 0);
    __syncthreads();
    int cur = 0;
    const int fr = lane & 15;
    const int lc0 = lane >> 4;
    const int px = lane & 7;
    const int arow_b = (w * 32 + fr) << 7;   // wave w owns output rows w*32..w*32+31
    const int brow_b = fr << 7;
    for (int kt = 0; kt < nk; ++kt) {
        if (kt + 1 < nk) STAGEN(cur ^ 1, kt + 1);
        const char* aP = (const char*)&aL[cur][0];
        const char* bP = (const char*)&bL[cur][0];
#pragma unroll
        for (int ksub = 0; ksub < 2; ++ksub) {
            const int cb = ((ksub * 4 + lc0) ^ px) << 4;
            s16x8 af[2], bf_[4];
#pragma unroll
            for (int mi = 0; mi < 2; ++mi) af[mi]  = *(const s16x8*)(aP + arow_b + mi * 2048 + cb);
#pragma unroll
            for (int ni = 0; ni < 4; ++ni) bf_[ni] = *(const s16x8*)(bP + brow_b + ni * 2048 + cb);
#pragma unroll
            for (int mi = 0; mi < 2; ++mi)
#pragma unroll
                for (int ni = 0; ni < 4; ++ni)
                    acc[mi][ni] = __builtin_amdgcn_mfma_f32_16x16x32_bf16(af[mi], bf_[ni], acc[mi][ni], 0, 0, 0);
        }
        __syncthreads();
        cur ^= 1;
    }
#undef STAGEN
    const int lr = (lane >> 4) * 4, lc = lane & 15;
    if (EPIN == 2) {
        bf16* cT = &aL[0][0];   // [128][72] padded tile (18KB) in dead 32KB aL
#pragma unroll
        for (int mi = 0; mi < 2; ++mi) {
            const int row0 = w * 32 + mi * 16 + lr;
            const int gr0 = m0 + row0;
#pragma unroll
            for (int ni = 0; ni < 4; ++ni) {
                const int colL = ni * 16 + lc;
                const int gc = n0 + colL;
                const float bv = bias[gc];
                unsigned short pk[4];
#pragma unroll
                for (int j = 0; j < 4; ++j) {
                    const bf16 hv = __float2bfloat16(acc[mi][ni][j] + bv);
                    cT[(row0 + j) * 72 + colL] = hv;
                    pk[j] = (gr0 + j < M) ? __builtin_bit_cast(unsigned short, hv)
                                          : (unsigned short)0;
                }
                if (gc >= 1024 && gc < 1536) {   // fused V-transpose (uniform per 16-lane group)
                    const int d = gc - 1024;
                    const int bb2 = gr0 / NROW, jj = gr0 - bb2 * NROW;
                    if (jj <= 1021 && gr0 + 3 < M) {
                        u64 pack =  (u64)pk[0] | ((u64)pk[1] << 16)
                                 | ((u64)pk[2] << 32) | ((u64)pk[3] << 48);
                        *(u64*)&vTout[((long)bb2 * 512 + d) * JSTR + jj] = pack;
                    } else {
#pragma unroll
                        for (int j = 0; j < 4; ++j) {
                            const int gr = gr0 + j;
                            if (gr < M) {
                                const int b3 = gr / NROW, j3 = gr - b3 * NROW;
                                vTout[((long)b3 * 512 + d) * JSTR + j3] =
                                    __builtin_bit_cast(bf16, pk[j]);
                            }
                        }
                    }
                }
            }
        }
        __syncthreads();
        const int row = tid >> 1, half = tid & 1;
        const int gr = m0 + row;
        if (gr < M) {
            bf16* dst = Cb + (long)gr * N + n0 + half * 32;
            const bf16* srcRow = cT + row * 72 + half * 32;
#pragma unroll
            for (int k = 0; k < 4; ++k)
                *(s16x8*)(dst + k * 8) = *(const s16x8*)(srcRow + k * 8);
        }
    } else {
#pragma unroll
        for (int mi = 0; mi < 2; ++mi) {
            const int gr0 = m0 + w * 32 + mi * 16 + lr;
#pragma unroll
            for (int ni = 0; ni < 4; ++ni) {
                const int gc = n0 + ni * 16 + lc;
                const float bv = bias[gc];
#pragma unroll
                for (int j = 0; j < 4; ++j) {
                    const int gr = gr0 + j;
                    if (gr < M) {
                        const float v = acc[mi][ni][j] + bv;
                        if (EPIN == 0) {
                            Cf[(long)gr * N + gc] += v;
                        } else {
                            const float g = 0.5f * v * (1.f + erff(v * 0.70710678118f));
                            Cb[(long)gr * N + gc] = __float2bfloat16(g);
                        }
                    }
                }
            }
        }
    }
    (void)vTout;
}

// ---------------------------------------------------------------- qg projection (r7/r12 proven): qg_all[b][c]
__global__ __launch_bounds__(256) void qg_proj(
    const bf16* __restrict__ ybf, const float* __restrict__ wqg,
    const float* __restrict__ bqg, float* __restrict__ qg_all)
{
    __shared__ float y0[512];
    const int b = blockIdx.x, tid = threadIdx.x;
    const long rowb = (long)b * NROW;
    for (int d = tid; d < 512; d += 256) y0[d] = __bfloat162float(ybf[rowb * DIMD + d]);
    __syncthreads();
    const int c = blockIdx.y * 256 + tid;
    float a = 0.f;
#pragma unroll 8
    for (int kk = 0; kk < 512; ++kk) a += y0[kk] * wqg[(long)kk * DIMD + c];
    qg_all[b * DIMD + c] = (a + bqg[c]) * 0.125f;
}

// ---------------------------------------------------------------- band + tiled-global attention (one launch, r12 proven)
__global__ __launch_bounds__(256) void band_glob_attn(
    const bf16* __restrict__ qkv, const bf16* __restrict__ vT,
    const float* __restrict__ qg_all, float* __restrict__ gpart, float* __restrict__ x)
{
    __shared__ bf16 KlPl[193 * 72];     // 27792 B: K rows (QK^T phase) / Pl (PV phase) / glob scratch
    __shared__ bf16 Vt[64 * 192];       // 24576 B, [d][k], byte ^= (d&7)<<4
    const int c = blockIdx.x, h = blockIdx.y, b = blockIdx.z;
    const int tid = threadIdx.x, lane = tid & 63, w = tid >> 6;
    const long rowb = (long)b * NROW;
    const int hoff = h * HD;

    if (c >= 16) {
        // ---------------- glob j-tile: keys j0..j0+len-1 vs qg
        const int t = c - 16;                 // 0..GTILE-1
        const int j0 = t * 129;
        const int len = (1025 - j0) < 129 ? (1025 - j0) : 129;
        float* gsh  = (float*)KlPl;
        float* S    = gsh;                    // 129
        float* qgs  = gsh + 160;              // 64
        float* redx = gsh + 224;              // 256
        const int dd = tid & 63, part = tid >> 6;
        if (tid < 64) qgs[tid] = qg_all[b * DIMD + hoff + tid];
        __syncthreads();
        if (tid < len) {
            const bf16* kr = qkv + (rowb + j0 + tid) * QKVN + 1536 + hoff;
            float s = 0.f;
#pragma unroll
            for (int c8 = 0; c8 < 8; ++c8) {
                s16x8 kv = *(const s16x8*)(kr + c8 * 8);
#pragma unroll
                for (int e = 0; e < 8; ++e) s += qgs[c8 * 8 + e] * b2f(kv[e]);
            }
            S[tid] = s;
        }
        __syncthreads();
        float lm = -1e30f;
        for (int j = tid; j < len; j += 256) lm = fmaxf(lm, S[j]);
        redx[tid] = lm; __syncthreads();
        for (int st = 128; st; st >>= 1) { if (tid < st) redx[tid] = fmaxf(redx[tid], redx[tid + st]); __syncthreads(); }
        const float mt = redx[0]; __syncthreads();
        float ls = 0.f;
        for (int j = tid; j < len; j += 256) { float e = __expf(S[j] - mt); S[j] = e; ls += e; }
        redx[tid] = ls; __syncthreads();
        for (int st = 128; st; st >>= 1) { if (tid < st) redx[tid] += redx[tid + st]; __syncthreads(); }
        const float tsum = redx[0];
        __syncthreads();
        float acc = 0.f;
#pragma unroll 4
        for (int j = part; j < len; j += 4)
            acc += S[j] * __bfloat162float(qkv[(rowb + j0 + j) * QKVN + 2048 + hoff + dd]);
        redx[tid] = acc;
        __syncthreads();
        if (part == 0) {
            float* gp = gpart + ((size_t)((b * NHEAD + h) * GTILE + t)) * 66;
            gp[2 + dd] = redx[dd] + redx[64 + dd] + redx[128 + dd] + redx[192 + dd];
            if (dd == 0) { gp[0] = mt; gp[1] = tsum; }
        }
        return;
    }

    // ---------------- band chunk (r11-proven path, unchanged)
    const int qi0 = 1 + c * 64, jbase = qi0 - 64;
    bf16* Kl = KlPl;

    for (int task = tid; task < 193 * 8; task += 256) {
        const int d8 = task & 7, r = task >> 3;
        int j = (r < 192) ? (jbase + r) : 0;
        j = j < 0 ? 0 : (j > 1024 ? 1024 : j);
        s16x8 val = *(const s16x8*)(qkv + (rowb + j) * QKVN + 512 + hoff + d8 * 8);
        *(s16x8*)(Kl + r * 72 + d8 * 8) = val;
    }
    for (int task = tid; task < 64 * 24; task += 256) {
        const int kc = task % 24, d = task / 24;
        int j0 = jbase + kc * 8;
        j0 = j0 < 0 ? 0 : (j0 > 1017 ? 1017 : j0);
        s16x8 v = *(const s16x8*)(vT + ((long)(b * 512 + hoff + d)) * JSTR + j0);
        const int bo = (d * 384 + kc * 16) ^ ((d & 7) << 4);
        *(s16x8*)((char*)Vt + bo) = v;
    }

    const int q = lane & 15, g = lane >> 4;
    const int qg = w * 16 + q;
    s16x8 qf0, qf1;
    {
        const bf16* qp = qkv + (rowb + qi0 + qg) * QKVN + hoff + g * 8;
        qf0 = *(const s16x8*)qp;
        qf1 = *(const s16x8*)(qp + 32);
    }
    __syncthreads();

    f32x4 sc[13] = {};
#pragma unroll
    for (int nt = 0; nt < 13; ++nt) {
        const bf16* kp = Kl + (nt * 16 + q) * 72 + g * 8;
        s16x8 k0 = *(const s16x8*)kp;
        s16x8 k1 = *(const s16x8*)(kp + 32);
        sc[nt] = __builtin_amdgcn_mfma_f32_16x16x32_bf16(k0, qf0, sc[nt], 0, 0, 0);
        sc[nt] = __builtin_amdgcn_mfma_f32_16x16x32_bf16(k1, qf1, sc[nt], 0, 0, 0);
    }

    const int lo_ = (qg > 1 - jbase) ? qg : 1 - jbase;
    const int hi_ = (qg + 128 < 1024 - jbase) ? qg + 128 : 1024 - jbase;
    float m = -1e30f;
#pragma unroll
    for (int nt = 0; nt < 12; ++nt)
#pragma unroll
        for (int j = 0; j < 4; ++j) {
            const int slot = nt * 16 + g * 4 + j;
            float s = (slot >= lo_ && slot <= hi_) ? sc[nt][j] : -1e9f;
            sc[nt][j] = s;
            m = fmaxf(m, s);
        }
#pragma unroll
    for (int j = 0; j < 4; ++j) {
        float s = (g == 0 && j == 0) ? sc[12][j] : -1e9f;
        sc[12][j] = s;
        m = fmaxf(m, s);
    }
    m = fmaxf(m, __shfl_xor(m, 16));
    m = fmaxf(m, __shfl_xor(m, 32));
    float sum = 0.f;
#pragma unroll
    for (int nt = 0; nt < 13; ++nt)
#pragma unroll
        for (int j = 0; j < 4; ++j) {
            float p = __expf(sc[nt][j] - m);
            sc[nt][j] = p;
            sum += p;
        }
    sum += __shfl_xor(sum, 16);
    sum += __shfl_xor(sum, 32);
    const float inv = 1.f / sum;
    const float a0 = __shfl(sc[12][0], q);

    __syncthreads();   // all waves done reading Kl before Pl overwrites it

    char* plw = (char*)KlPl + w * 6144;
#pragma unroll
    for (int nt = 0; nt < 12; ++nt) {
        u32 lo2 = (u32)f2bfbits(sc[nt][0]) | ((u32)f2bfbits(sc[nt][1]) << 16);
        u32 hi2 = (u32)f2bfbits(sc[nt][2]) | ((u32)f2bfbits(sc[nt][3]) << 16);
        const int bo = (q * 384 + (nt * 16 + g * 4) * 2) ^ ((q & 7) << 4);
        *(uint2*)(plw + bo) = make_uint2(lo2, hi2);
    }
    __syncthreads();

    f32x4 ac[4] = {};
#pragma unroll
    for (int ks = 0; ks < 6; ++ks) {
        const int pbo = (q * 384 + (ks * 32 + g * 8) * 2) ^ ((q & 7) << 4);
        s16x8 pf = *(const s16x8*)(plw + pbo);
#pragma unroll
        for (int mt = 0; mt < 4; ++mt) {
            const int d = mt * 16 + q;
            const int vbo = ((d * 192 + ks * 32 + g * 8) * 2) ^ ((d & 7) << 4);
            s16x8 vf = *(const s16x8*)((char*)Vt + vbo);
            ac[mt] = __builtin_amdgcn_mfma_f32_16x16x32_bf16(vf, pf, ac[mt], 0, 0, 0);
        }
    }

    const bf16* v0p = qkv + rowb * QKVN + 1024 + hoff;
    float* xr = x + (rowb + qi0 + qg) * DIMD + hoff;
#pragma unroll
    for (int mt = 0; mt < 4; ++mt) {
        const int d0 = mt * 16 + g * 4;
        const s16x4 vv = *(const s16x4*)(v0p + d0);
        float4 prev = *(float4*)(xr + d0);
        prev.x += (ac[mt][0] + a0 * b2f(vv[0])) * inv;
        prev.y += (ac[mt][1] + a0 * b2f(vv[1])) * inv;
        prev.z += (ac[mt][2] + a0 * b2f(vv[2])) * inv;
        prev.w += (ac[mt][3] + a0 * b2f(vv[3])) * inv;
        *(float4*)(xr + d0) = prev;
    }
}

// ---------------------------------------------------------------- LN of 8 cls rows -> f32
__global__ __launch_bounds__(512) void lncls(
    const float* __restrict__ x, const float* __restrict__ lw,
    const float* __restrict__ lb, float* __restrict__ out)
{
    const int b = threadIdx.x >> 6, lane = threadIdx.x & 63;
    const int d0 = lane * 8;
    const float* xr = x + (long)b * NROW * DIMD + d0;
    float4 a = *(const float4*)xr;
    float4 b4 = *(const float4*)(xr + 4);
    float s  = a.x + a.y + a.z + a.w + b4.x + b4.y + b4.z + b4.w;
    float sq = a.x*a.x + a.y*a.y + a.z*a.z + a.w*a.w + b4.x*b4.x + b4.y*b4.y + b4.z*b4.z + b4.w*b4.w;
#pragma unroll
    for (int o = 32; o; o >>= 1) { s += __shfl_xor(s, o); sq += __shfl_xor(sq, o); }
    const float mean = s * (1.f / 512.f);
    const float rstd = rsqrtf(sq * (1.f / 512.f) - mean * mean + 1e-5f);
    float vals[8] = {a.x, a.y, a.z, a.w, b4.x, b4.y, b4.z, b4.w};
#pragma unroll
    for (int u = 0; u < 8; ++u)
        out[b * DIMD + d0 + u] = (vals[u] - mean) * rstd * lw[d0 + u] + lb[d0 + u];
}

// ---------------------------------------------------------------- head GEMV: thread per (b, class)
__global__ __launch_bounds__(128) void head_gemv(
    const float* __restrict__ lnc, const float* __restrict__ hw,
    const float* __restrict__ hb, float* __restrict__ out)
{
    const int idx = blockIdx.x * 128 + threadIdx.x;
    if (idx >= NB * 1000) return;
    const int b = idx / 1000, cc = idx - b * 1000;
    const float* lr = lnc + b * DIMD;
    float a = hb[cc];
#pragma unroll 8
    for (int kk = 0; kk < 512; ++kk) a += lr[kk] * hw[(long)kk * 1000 + cc];
    out[idx] = a;
}

// ================================================================ launch
extern "C" void kernel_launch(void* const* d_in, const int* in_sizes, int n_in,
                              void* d_out, int out_size, void* d_ws, size_t ws_size,
                              hipStream_t stream)
{
    const float* img     = (const float*)d_in[0];
    const float* patch_w = (const float*)d_in[1];
    const float* patch_b = (const float*)d_in[2];
    const float* cls_tok = (const float*)d_in[3];
    const float* pos_emb = (const float*)d_in[4];
    const float* ln1_w   = (const float*)d_in[5];
    const float* ln1_b   = (const float*)d_in[6];
    const float* wq  = (const float*)d_in[7];
    const float* bq  = (const float*)d_in[8];
    const float* wk  = (const float*)d_in[9];
    const float* bk  = (const float*)d_in[10];
    const float* wv  = (const float*)d_in[11];
    const float* bv  = (const float*)d_in[12];
    const float* wqg = (const float*)d_in[13];
    const float* bqg = (const float*)d_in[14];
    const float* wkg = (const float*)d_in[15];
    const float* bkg = (const float*)d_in[16];
    const float* wvg = (const float*)d_in[17];
    const float* bvg = (const float*)d_in[18];
    const float* ln2_w = (const float*)d_in[19];
    const float* ln2_b = (const float*)d_in[20];
    const float* w1 = (const float*)d_in[21];
    const float* b1 = (const float*)d_in[22];
    const float* w2 = (const float*)d_in[23];
    const float* b2 = (const float*)d_in[24];
    const float* hlw = (const float*)d_in[25];
    const float* hlb = (const float*)d_in[26];
    const float* hw  = (const float*)d_in[27];
    const float* hb  = (const float*)d_in[28];

    char* wsb = (char*)d_ws;
    size_t o = 0;
    auto carve = [&](size_t n) { size_t r = o; o += (n + 255) & ~(size_t)255; return r; };
    float* x    = (float*)(wsb + carve((size_t)MTOT * DIMD * 4));
    bf16*  ybf  = (bf16*) (wsb + carve((size_t)MTOT * DIMD * 2));
    bf16*  qkv  = (bf16*) (wsb + carve((size_t)MTOT * QKVN * 2));
    bf16*  hbuf = (bf16*) (wsb + carve((size_t)MTOT * MLPD * 2));
    bf16*  vT   = (bf16*) (wsb + carve((size_t)NB * 512 * JSTR * 2));
    bf16*  acol = (bf16*) (wsb + carve((size_t)8192 * 768 * 2));
    bf16*  pwt  = (bf16*) (wsb + carve((size_t)512 * 768 * 2));
    bf16*  qkvT = (bf16*) (wsb + carve((size_t)2 * QKVN * DIMD * 2));
    bf16*  w1t  = (bf16*) (wsb + carve((size_t)2 * MLPD * DIMD * 2));
    bf16*  w2t  = (bf16*) (wsb + carve((size_t)2 * DIMD * MLPD * 2));
    float* catb = (float*)(wsb + carve((size_t)2 * QKVN * 4));
    float* qg_all = (float*)(wsb + carve((size_t)NB * DIMD * 4));
    float* gpart  = (float*)(wsb + carve((size_t)NB * NHEAD * GTILE * 66 * 4));
    float* lnc  = (float*)(wsb + carve((size_t)NB * DIMD * 4));
    (void)ws_size; (void)in_sizes; (void)n_in; (void)out_size;

    dim3 tb(32, 8);
    transpose_cvt_L<<<dim3(16, 24, 1), tb, 0, stream>>>(patch_w, pwt, 768, 512, 1.f);
    qkvw_t<<<dim3(16, 16, 10), tb, 0, stream>>>(wq, wk, wv, wkg, wvg, qkvT);
    transpose_cvt_L<<<dim3(64, 16, 2), tb, 0, stream>>>(w1, w1t, DIMD, MLPD, 1.f);
    transpose_cvt_L<<<dim3(16, 64, 2), tb, 0, stream>>>(w2, w2t, MLPD, DIMD, 1.f);
    build_bias<<<20, 256, 0, stream>>>(bq, bk, bv, bkg, bvg, catb);

    im2col<<<4096, 256, 0, stream>>>(img, acol);
    gemm128<4><<<dim3(4, 64), 256, 0, stream>>>(
        acol, pwt, patch_b, x, nullptr, 8192, 512, 768, pos_emb, nullptr);
    cls_row<<<16, 256, 0, stream>>>(cls_tok, pos_emb, x);

    for (int L = 0; L < 2; ++L) {
        ln_fwd<<<2050, 256, 0, stream>>>(x, ln1_w + L * DIMD, ln1_b + L * DIMD, ybf, MTOT, nullptr);
        gemm_n64<2><<<dim3(QKVN/64, 65), 256, 0, stream>>>(
            ybf, qkvT + (size_t)L * QKVN * DIMD, catb + L * QKVN, nullptr, qkv,
            MTOT, QKVN, DIMD, vT);
        qg_proj<<<dim3(NB, 2), 256, 0, stream>>>(
            ybf, wqg + (size_t)L * DIMD * DIMD, bqg + L * DIMD, qg_all);
        band_glob_attn<<<dim3(16 + GTILE, NHEAD, NB), 256, 0, stream>>>(
            qkv, vT, qg_all, gpart, x);
        ln_fwd<<<2050, 256, 0, stream>>>(x, ln2_w + L * DIMD, ln2_b + L * DIMD, ybf, MTOT, gpart);
        gemm_n64<1><<<dim3(MLPD/64, 65), 256, 0, stream>>>(
            ybf, w1t + (size_t)L * MLPD * DIMD, b1 + L * MLPD, nullptr, hbuf,
            MTOT, MLPD, DIMD, nullptr);
        gemm_n64<0><<<dim3(DIMD/64, 65), 256, 0, stream>>>(
            hbuf, w2t + (size_t)L * DIMD * MLPD, b2 + L * DIMD, x, nullptr,
            MTOT, DIMD, MLPD, nullptr);
    }
    lncls<<<1, 512, 0, stream>>>(x, hlw, hlb, lnc);
    head_gemv<<<63, 128, 0, stream>>>(lnc, hw, hb, (float*)d_out);
}